// Round 5
// baseline (250.316 us; speedup 1.0000x reference)
//
#include <hip/hip_runtime.h>
#include <hip/hip_bf16.h>

// ---------------- problem constants ----------------
#define B_TOTAL   32768
#define L_SITES   256
#define N_MID     254        // L-2 middle sites
#define N_PAIR    127        // merged site-pairs
#define HALF_PI_F 1.57079632679489662f
#define EPS_NORM  1e-8f

// ---------------- ws layout (float/dword slots) ----------------
// [WS_FRAG .. +520191]  PAIR-table: 127 pairs x 16 frags x 64 lanes x 4 dwords
//                       frag q = c2b*4 + h*2 + pp
//                         c2b = f1*2+f2 (feature combo), h = c-half, pp: 0=hi,1=lo
//                       entries: T[a][m] with T = A_{2p,f1} @ A_{2p+1,f2} (fp32),
//                       contraction axis PI-PERMUTED (k-slot (quad,j) holds
//                       a = (j<4 ? quad*4+j : 16+quad*4+j-4)) so the swapped-MFMA
//                       output feeds the next pair with no transpose.
// [WS_C0   .. +63]      core0 fp32  [f][32]
// [WS_CN   .. +639]     coreN fp32  [f][a][10]
// [WS_X    .. +8388607] xT fp32 [L][B]  (transposed)
// [WS_FLAG]             u32 flag: 1 = inputs are bf16, 0 = fp32
#define WS_FRAG 0
#define WS_C0   520192
#define WS_CN   520256
#define WS_X    520896
#define WS_FLAG 8909504

typedef short bf16x8 __attribute__((ext_vector_type(8)));
typedef float f32x4  __attribute__((ext_vector_type(4)));

// pi-permutation of the contraction axis (k-slot -> actual a index)
__device__ __host__ __forceinline__ int pi_perm(int quad, int j) {
    return (j < 4) ? (quad * 4 + j) : (16 + quad * 4 + (j - 4));
}

__device__ __forceinline__ unsigned short f2bf(float f) {
    unsigned u = __builtin_bit_cast(unsigned, f);
    u += 0x7FFFu + ((u >> 16) & 1u);          // RNE
    return (unsigned short)(u >> 16);
}
__device__ __forceinline__ float bf2f(unsigned short h) {
    unsigned u = ((unsigned)h) << 16;
    return __builtin_bit_cast(float, u);
}
__device__ __forceinline__ bf16x8 asbf(uint4 u) {
    return __builtin_bit_cast(bf16x8, u);
}
// packed RNE f32x2 -> bf16x2 (lowers to v_cvt_pk_bf16_f32)
__device__ __forceinline__ unsigned pkbf2(float a, float b) {
    float2 p; p.x = a; p.y = b;
    __hip_bfloat162 h2 = __float22bfloat162_rn(p);
    unsigned u;
    __builtin_memcpy(&u, &h2, 4);
    return u;                                  // a in bits 0..15, b in 16..31
}
// split 8 fp32 into hi/lo bf16 fragments via packed cvt (RNE, proven)
__device__ __forceinline__ void split8(const float* v, bf16x8& hi, bf16x8& lo) {
    uint4 H, L;
    unsigned* hp = (unsigned*)&H;
    unsigned* lp = (unsigned*)&L;
    #pragma unroll
    for (int d = 0; d < 4; ++d) {
        float a = v[2 * d], b = v[2 * d + 1];
        unsigned hb = pkbf2(a, b);
        float h0 = __builtin_bit_cast(float, hb << 16);
        float h1 = __builtin_bit_cast(float, hb & 0xFFFF0000u);
        hp[d] = hb;
        lp[d] = pkbf2(a - h0, b - h1);         // exact residuals
    }
    hi = __builtin_bit_cast(bf16x8, H);
    lo = __builtin_bit_cast(bf16x8, L);
}
// per-wave input-dtype flag: bf16 pairs always have low16 < 0x4000
__device__ __forceinline__ bool detect_bf16(const unsigned* x_raw, int lane) {
    unsigned v = x_raw[lane];
    return __ballot((v & 0xFFFFu) >= 0x4000u) == 0ull;
}

// ---------------- fused aux kernel ----------------
// blocks [0,2048)      : x transpose [B][L] -> xT [L][B] fp32 (vectorized)
// blocks [2048,2175)   : PAIR builder — one block per pair p:
//                        stage A_{2p}, A_{2p+1} in LDS (coalesced), compute
//                        P = A1@A2 per feature combo in fp32, split hi/lo.
// block  2175          : small cores -> fp32, + WS_FLAG write
__global__ __launch_bounds__(256)
void aux_all(const void* __restrict__ x_in, const void* __restrict__ c0_in,
             const void* __restrict__ am_in, const void* __restrict__ cn_in,
             float* __restrict__ ws) {
    const int lane = threadIdx.x & 63;
    const bool bf = detect_bf16((const unsigned*)x_in, lane);
    const int b = blockIdx.x;

    if (b < 2048) {
        __shared__ float tile[64][65];          // tile[b_local][l_local], +1 pad
        const int bb = (b & 511) * 64;
        const int ll = (b >> 9) * 64;
        if (!bf) {
            const float4* x4 = (const float4*)x_in;   // row = 64 float4
            const int tr = threadIdx.x >> 4;    // 0..15
            const int q  = threadIdx.x & 15;    // 0..15
            #pragma unroll
            for (int u = 0; u < 4; ++u) {
                int row = tr + u * 16;
                float4 v = x4[(size_t)(bb + row) * (L_SITES / 4) + (ll / 4) + q];
                tile[row][q * 4 + 0] = v.x;
                tile[row][q * 4 + 1] = v.y;
                tile[row][q * 4 + 2] = v.z;
                tile[row][q * 4 + 3] = v.w;
            }
        } else {
            const uint4* x8 = (const uint4*)x_in;     // row = 32 uint4 (8 bf16 each)
            const int tr = threadIdx.x >> 3;    // 0..31
            const int q  = threadIdx.x & 7;     // 0..7
            #pragma unroll
            for (int u = 0; u < 2; ++u) {
                int row = tr + u * 32;
                uint4 v = x8[(size_t)(bb + row) * (L_SITES / 8) + (ll / 8) + q];
                const unsigned short* e = (const unsigned short*)&v;
                #pragma unroll
                for (int k = 0; k < 8; ++k) tile[row][q * 8 + k] = bf2f(e[k]);
            }
        }
        __syncthreads();
        {
            const int tr = threadIdx.x >> 4;    // 0..15
            const int q  = threadIdx.x & 15;    // 0..15
            float4* o4 = (float4*)(ws + WS_X);
            #pragma unroll
            for (int u = 0; u < 4; ++u) {
                int site = tr + u * 16;         // l_local
                float4 v;
                v.x = tile[q * 4 + 0][site];
                v.y = tile[q * 4 + 1][site];
                v.z = tile[q * 4 + 2][site];
                v.w = tile[q * 4 + 3][site];
                o4[((size_t)(ll + site) * B_TOTAL + bb) / 4 + q] = v;
            }
        }
    } else if (b < 2048 + N_PAIR) {
        const int p = b - 2048;
        // a1t[f][e][a] = A_{2p}[f][a][e] (transposed for conflict-light dot reads)
        // a2 [f][e][m] = A_{2p+1}[f][e][m] (linear copy)
        __shared__ float a1t[2][32][32];
        __shared__ float a2 [2][32][32];
        const unsigned short* us = (const unsigned short*)am_in;
        const float* fl = (const float*)am_in;
        for (int idx = threadIdx.x; idx < 4096; idx += 256) {
            int which = idx >> 11;              // 0: A1, 1: A2
            int off   = idx & 2047;             // [f][a][e] linear
            size_t gi = (size_t)(2 * p + which) * 2048 + off;
            float v = bf ? bf2f(us[gi]) : fl[gi];
            if (which == 0) {
                int f = off >> 10, a = (off >> 5) & 31, e = off & 31;
                a1t[f][e][a] = v;
            } else {
                ((float*)a2)[off] = v;
            }
        }
        __syncthreads();
        // compute: thread = (combo c2b = tid>>6, lane l = tid&63)
        const int l   = threadIdx.x & 63;
        const int c2b = threadIdx.x >> 6;       // f1*2+f2
        const int f1  = c2b >> 1, f2 = c2b & 1;
        const int m0  = l & 15;                 // h=0 output col
        const int m1  = 16 + (l & 15);          // h=1 output col
        unsigned H0[4], L0[4], H1[4], L1[4];
        #pragma unroll
        for (int d = 0; d < 4; ++d) {
            unsigned h0 = 0, l0 = 0, h1 = 0, l1 = 0;
            #pragma unroll
            for (int s = 0; s < 2; ++s) {
                int k = (l >> 4) * 8 + 2 * d + s;
                int a = pi_perm(k >> 3, k & 7);
                float v0 = 0.f, v1 = 0.f;
                #pragma unroll 8
                for (int e = 0; e < 32; ++e) {
                    float t = a1t[f1][e][a];
                    v0 = fmaf(t, a2[f2][e][m0], v0);
                    v1 = fmaf(t, a2[f2][e][m1], v1);
                }
                unsigned short vh0 = f2bf(v0);
                unsigned short vl0 = f2bf(v0 - bf2f(vh0));
                unsigned short vh1 = f2bf(v1);
                unsigned short vl1 = f2bf(v1 - bf2f(vh1));
                h0 |= ((unsigned)vh0) << (16 * s);
                l0 |= ((unsigned)vl0) << (16 * s);
                h1 |= ((unsigned)vh1) << (16 * s);
                l1 |= ((unsigned)vl1) << (16 * s);
            }
            H0[d] = h0; L0[d] = l0; H1[d] = h1; L1[d] = l1;
        }
        uint4* o = (uint4*)ws;
        const size_t base = ((size_t)p * 16 + c2b * 4) * 64 + l;
        uint4 u;
        u.x = H0[0]; u.y = H0[1]; u.z = H0[2]; u.w = H0[3]; o[base]           = u;  // h0 hi
        u.x = L0[0]; u.y = L0[1]; u.z = L0[2]; u.w = L0[3]; o[base + 64]      = u;  // h0 lo
        u.x = H1[0]; u.y = H1[1]; u.z = H1[2]; u.w = H1[3]; o[base + 128]     = u;  // h1 hi
        u.x = L1[0]; u.y = L1[1]; u.z = L1[2]; u.w = L1[3]; o[base + 192]     = u;  // h1 lo
    } else {
        for (int i = threadIdx.x; i < 640; i += 256) {
            if (i < 64)
                ws[WS_C0 + i] = bf ? bf2f(((const unsigned short*)c0_in)[i])
                                   : ((const float*)c0_in)[i];
            ws[WS_CN + i] = bf ? bf2f(((const unsigned short*)cn_in)[i])
                               : ((const float*)cn_in)[i];
        }
        if (threadIdx.x == 0)
            *(unsigned*)(ws + WS_FLAG) = bf ? 1u : 0u;
    }
}

// ---------------- main chain kernel ----------------
// Round-4 skeleton (independent waves, register prefetch, no LDS, no barriers)
// + THIS ROUND: site-PAIR merging. 127 pair-steps instead of 254 site-steps:
// M'' = sum_{f1,f2} s1_{f1} s2_{f2} P_{f1f2}-applied M, P precomputed in aux.
// Per pair: ONE split8, 24 MFMAs as 8 independent 3-deep chains, one 4-term
// per-sample combine. Halves the serial stage count (the round-0..4 counters
// showed a latency-bound chain: no pipe >52% busy at 2 waves/SIMD).
// Norm cadence maps exactly: pairs 3,7,...,123 (= sites 7,...,247) + final
// pair 126 (= site 253) — identical to the passing kernel.
__global__ __launch_bounds__(256, 2)
void mps_mfma(const float* __restrict__ ws, void* __restrict__ out) {
    const int lane = threadIdx.x & 63;
    const int w    = threadIdx.x >> 6;
    const int r    = lane & 15;
    const int quad = lane >> 4;
    const int b0   = (blockIdx.x * 4 + w) * 16;
    const float* __restrict__ xT = ws + WS_X;
    const uint4* __restrict__ BF = (const uint4*)ws;   // WS_FRAG = 0
    const int i = b0 + r;

    // ---- M0 in pi-layout: mm[j] = M0[b=r][a=pi(quad,j)] ----
    float mm[8];
    {
        float x0 = xT[i];
        float sn, cs; __sincosf(HALF_PI_F * x0, &sn, &cs);
        const float* c0 = ws + WS_C0;
        #pragma unroll
        for (int j = 0; j < 8; ++j) {
            int a = pi_perm(quad, j);
            mm[j] = cs * c0[a] + sn * c0[32 + a];
        }
    }

// load 16 pair-frags (q*1024B immediate offsets off one base)
#define LOADF(F, P)                                                                \
    {                                                                              \
        const uint4* BP_ = BF + (size_t)(P) * 1024 + lane;                         \
        _Pragma("unroll")                                                          \
        for (int q = 0; q < 16; ++q) (F)[q] = BP_[q * 64];                         \
    }

// one PAIR step: split M once -> 24 MFMA (8 indep 3-chains) -> 4-term
// post-scale combine with (C1*C2, C1*S2, S1*C2, S1*S2) -> optional norm.
// Frag q = c2b*4 + h*2 + pp.  Acc Ach: c2b in {0..3}, h in {0,1}.
#define DO_PAIR(C1, S1, C2, S2, F, DONORM)                                         \
    {                                                                              \
        bf16x8 mh, ml;                                                             \
        split8(mm, mh, ml);                                                        \
        const f32x4 z = {0.f, 0.f, 0.f, 0.f};                                      \
        __builtin_amdgcn_s_setprio(1);                                             \
        f32x4 A00 = __builtin_amdgcn_mfma_f32_16x16x32_bf16(asbf((F)[0]),  mh, z, 0, 0, 0); \
        f32x4 A01 = __builtin_amdgcn_mfma_f32_16x16x32_bf16(asbf((F)[2]),  mh, z, 0, 0, 0); \
        f32x4 A10 = __builtin_amdgcn_mfma_f32_16x16x32_bf16(asbf((F)[4]),  mh, z, 0, 0, 0); \
        f32x4 A11 = __builtin_amdgcn_mfma_f32_16x16x32_bf16(asbf((F)[6]),  mh, z, 0, 0, 0); \
        f32x4 A20 = __builtin_amdgcn_mfma_f32_16x16x32_bf16(asbf((F)[8]),  mh, z, 0, 0, 0); \
        f32x4 A21 = __builtin_amdgcn_mfma_f32_16x16x32_bf16(asbf((F)[10]), mh, z, 0, 0, 0); \
        f32x4 A30 = __builtin_amdgcn_mfma_f32_16x16x32_bf16(asbf((F)[12]), mh, z, 0, 0, 0); \
        f32x4 A31 = __builtin_amdgcn_mfma_f32_16x16x32_bf16(asbf((F)[14]), mh, z, 0, 0, 0); \
        A00 = __builtin_amdgcn_mfma_f32_16x16x32_bf16(asbf((F)[1]),  mh, A00, 0, 0, 0); \
        A01 = __builtin_amdgcn_mfma_f32_16x16x32_bf16(asbf((F)[3]),  mh, A01, 0, 0, 0); \
        A10 = __builtin_amdgcn_mfma_f32_16x16x32_bf16(asbf((F)[5]),  mh, A10, 0, 0, 0); \
        A11 = __builtin_amdgcn_mfma_f32_16x16x32_bf16(asbf((F)[7]),  mh, A11, 0, 0, 0); \
        A20 = __builtin_amdgcn_mfma_f32_16x16x32_bf16(asbf((F)[9]),  mh, A20, 0, 0, 0); \
        A21 = __builtin_amdgcn_mfma_f32_16x16x32_bf16(asbf((F)[11]), mh, A21, 0, 0, 0); \
        A30 = __builtin_amdgcn_mfma_f32_16x16x32_bf16(asbf((F)[13]), mh, A30, 0, 0, 0); \
        A31 = __builtin_amdgcn_mfma_f32_16x16x32_bf16(asbf((F)[15]), mh, A31, 0, 0, 0); \
        A00 = __builtin_amdgcn_mfma_f32_16x16x32_bf16(asbf((F)[0]),  ml, A00, 0, 0, 0); \
        A01 = __builtin_amdgcn_mfma_f32_16x16x32_bf16(asbf((F)[2]),  ml, A01, 0, 0, 0); \
        A10 = __builtin_amdgcn_mfma_f32_16x16x32_bf16(asbf((F)[4]),  ml, A10, 0, 0, 0); \
        A11 = __builtin_amdgcn_mfma_f32_16x16x32_bf16(asbf((F)[6]),  ml, A11, 0, 0, 0); \
        A20 = __builtin_amdgcn_mfma_f32_16x16x32_bf16(asbf((F)[8]),  ml, A20, 0, 0, 0); \
        A21 = __builtin_amdgcn_mfma_f32_16x16x32_bf16(asbf((F)[10]), ml, A21, 0, 0, 0); \
        A30 = __builtin_amdgcn_mfma_f32_16x16x32_bf16(asbf((F)[12]), ml, A30, 0, 0, 0); \
        A31 = __builtin_amdgcn_mfma_f32_16x16x32_bf16(asbf((F)[14]), ml, A31, 0, 0, 0); \
        __builtin_amdgcn_s_setprio(0);                                             \
        float wcc = (C1) * (C2), wcs = (C1) * (S2);                                \
        float wsc = (S1) * (C2), wss = (S1) * (S2);                                \
        _Pragma("unroll")                                                          \
        for (int j = 0; j < 4; ++j) {                                              \
            mm[j]     = fmaf(wss, A30[j], fmaf(wsc, A20[j],                        \
                        fmaf(wcs, A10[j], wcc * A00[j])));                         \
            mm[4 + j] = fmaf(wss, A31[j], fmaf(wsc, A21[j],                        \
                        fmaf(wcs, A11[j], wcc * A01[j])));                         \
        }                                                                          \
        if (DONORM) {                                                              \
            float ss = 0.f;                                                        \
            _Pragma("unroll")                                                      \
            for (int j = 0; j < 8; ++j) ss = fmaf(mm[j], mm[j], ss);               \
            ss += __shfl_xor(ss, 16);                                              \
            ss += __shfl_xor(ss, 32);                                              \
            float kk = 1.0f / (sqrtf(ss) + EPS_NORM);                              \
            _Pragma("unroll")                                                      \
            for (int j = 0; j < 8; ++j) mm[j] *= kk;                               \
        }                                                                          \
    }

    // ---- pipeline prologue ----
    uint4 FA[16];
    LOADF(FA, 0);
    float c1, s1, c2, s2;                              // factors for pair 0
    { float xa = xT[(size_t)1 * B_TOTAL + i]; __sincosf(HALF_PI_F * xa, &s1, &c1); }
    { float xb = xT[(size_t)2 * B_TOTAL + i]; __sincosf(HALF_PI_F * xb, &s2, &c2); }
    float xp1 = xT[(size_t)3 * B_TOTAL + i];           // x rows for pair 1
    float xp2 = xT[(size_t)4 * B_TOTAL + i];

    #pragma unroll 1
    for (int it = 0; it < 63; ++it) {                  // pairs 2it, 2it+1
        const int p = 2 * it;
        // ---- even pair p: consume (c1..s2, FA); prep pair p+1 ----
        uint4 FB[16];
        LOADF(FB, p + 1);
        float c1n, s1n, c2n, s2n;
        __sincosf(HALF_PI_F * xp1, &s1n, &c1n);
        __sincosf(HALF_PI_F * xp2, &s2n, &c2n);
        xp1 = xT[(size_t)(2 * p + 5) * B_TOTAL + i];   // pair p+2 rows (<=255)
        xp2 = xT[(size_t)(2 * p + 6) * B_TOTAL + i];

        DO_PAIR(c1, s1, c2, s2, FA, false)

        // ---- odd pair p+1: consume (c1n..s2n, FB); prep pair p+2 ----
        LOADF(FA, p + 2);
        __sincosf(HALF_PI_F * xp1, &s1, &c1);
        __sincosf(HALF_PI_F * xp2, &s2, &c2);
        int r7 = 2 * p + 7; if (r7 > 255) r7 = 255;    // pair p+3 rows (clamped)
        int r8 = 2 * p + 8; if (r8 > 255) r8 = 255;
        xp1 = xT[(size_t)r7 * B_TOTAL + i];
        xp2 = xT[(size_t)r8 * B_TOTAL + i];

        DO_PAIR(c1n, s1n, c2n, s2n, FB, (it & 1) == 1)
    }
    // ---- tail pair 126 (frags + factors prepared by it=62 second half) ----
    DO_PAIR(c1, s1, c2, s2, FA, true)
#undef DO_PAIR
#undef LOADF

    // ---- readout: logits[r][c] = sum_a M[r][a]*(cN*KN0[a,c] + sN*KN1[a,c]) ----
    {
        float xN = xT[(size_t)(L_SITES - 1) * B_TOTAL + i];
        float sN, cN; __sincosf(HALF_PI_F * xN, &sN, &cN);
        const float* kn = ws + WS_CN;        // [f][a][10]
        float acc[10];
        #pragma unroll
        for (int c = 0; c < 10; ++c) acc[c] = 0.f;
        #pragma unroll
        for (int j = 0; j < 8; ++j) {
            int a = pi_perm(quad, j);
            float Ma = mm[j];
            #pragma unroll
            for (int c = 0; c < 10; ++c) {
                float fin = cN * kn[a * 10 + c] + sN * kn[320 + a * 10 + c];
                acc[c] = fmaf(Ma, fin, acc[c]);
            }
        }
        #pragma unroll
        for (int c = 0; c < 10; ++c) {
            acc[c] += __shfl_xor(acc[c], 16);
            acc[c] += __shfl_xor(acc[c], 32);
        }
        const unsigned bf = *(const unsigned*)(ws + WS_FLAG);
        if (quad == 0) {
            if (bf) {
                __hip_bfloat16* o = (__hip_bfloat16*)out;
                #pragma unroll
                for (int c = 0; c < 10; ++c)
                    o[(size_t)(b0 + r) * 10 + c] = __float2bfloat16(acc[c]);
            } else {
                float* o = (float*)out;
                #pragma unroll
                for (int c = 0; c < 10; ++c)
                    o[(size_t)(b0 + r) * 10 + c] = acc[c];
            }
        }
    }
}

// ---------------- launch ----------------
extern "C" void kernel_launch(void* const* d_in, const int* in_sizes, int n_in,
                              void* d_out, int out_size, void* d_ws, size_t ws_size,
                              hipStream_t stream) {
    float* ws = (float*)d_ws;
    aux_all<<<2048 + N_PAIR + 1, 256, 0, stream>>>(d_in[0], d_in[1], d_in[2], d_in[3], ws);
    // 512 blocks x 4 waves x 16 samples = 32768 samples; 2048 waves = 2 waves/SIMD
    mps_mfma<<<512, 256, 0, stream>>>(ws, d_out);
}

// Round 7
// 230.126 us; speedup vs baseline: 1.0877x; 1.0877x over previous
//
#include <hip/hip_runtime.h>
#include <hip/hip_bf16.h>

// ---------------- problem constants ----------------
#define B_TOTAL   32768
#define L_SITES   256
#define N_MID     254        // L-2 middle sites
#define HALF_PI_F 1.57079632679489662f
#define EPS_NORM  1e-8f

// ---------------- ws layout (float/dword slots) ----------------
// [WS_FRAG .. +520191]  A-operand fragment table: 254 steps x 8 frags x 64 lanes x 4 dwords
//                       frag q = h*4 + kh*2 + p  (h: c-half, kh: feature, p: 0=hi,1=lo)
//                       contraction axis PI-PERMUTED (k-slot (quad,j) holds
//                       a = (j<4 ? quad*4+j : 16+quad*4+j-4)) so the swapped-MFMA
//                       output feeds the next step with no transpose.
// [WS_C0   .. +63]      core0 fp32  [f][32]
// [WS_CN   .. +639]     coreN fp32  [f][a][10]
// [WS_X    .. +8388607] xT fp32 [L][B]  (transposed)
// [WS_FLAG]             u32 flag: 1 = inputs are bf16, 0 = fp32
#define WS_FRAG 0
#define WS_C0   520192
#define WS_CN   520256
#define WS_X    520896
#define WS_FLAG 8909504

typedef short bf16x8 __attribute__((ext_vector_type(8)));
typedef float f32x4  __attribute__((ext_vector_type(4)));

// pi-permutation of the contraction axis (k-slot -> actual a index)
__device__ __host__ __forceinline__ int pi_perm(int quad, int j) {
    return (j < 4) ? (quad * 4 + j) : (16 + quad * 4 + (j - 4));
}

__device__ __forceinline__ unsigned short f2bf(float f) {
    unsigned u = __builtin_bit_cast(unsigned, f);
    u += 0x7FFFu + ((u >> 16) & 1u);          // RNE
    return (unsigned short)(u >> 16);
}
__device__ __forceinline__ float bf2f(unsigned short h) {
    unsigned u = ((unsigned)h) << 16;
    return __builtin_bit_cast(float, u);
}
__device__ __forceinline__ bf16x8 asbf(uint4 u) {
    return __builtin_bit_cast(bf16x8, u);
}
// packed RNE f32x2 -> bf16x2 (lowers to v_cvt_pk_bf16_f32)
__device__ __forceinline__ unsigned pkbf2(float a, float b) {
    float2 p; p.x = a; p.y = b;
    __hip_bfloat162 h2 = __float22bfloat162_rn(p);
    unsigned u;
    __builtin_memcpy(&u, &h2, 4);
    return u;                                  // a in bits 0..15, b in 16..31
}
// split 8 fp32 into hi/lo bf16 fragments via packed cvt (RNE, proven)
__device__ __forceinline__ void split8(const float* v, bf16x8& hi, bf16x8& lo) {
    uint4 H, L;
    unsigned* hp = (unsigned*)&H;
    unsigned* lp = (unsigned*)&L;
    #pragma unroll
    for (int d = 0; d < 4; ++d) {
        float a = v[2 * d], b = v[2 * d + 1];
        unsigned hb = pkbf2(a, b);
        float h0 = __builtin_bit_cast(float, hb << 16);
        float h1 = __builtin_bit_cast(float, hb & 0xFFFF0000u);
        hp[d] = hb;
        lp[d] = pkbf2(a - h0, b - h1);         // exact residuals
    }
    hi = __builtin_bit_cast(bf16x8, H);
    lo = __builtin_bit_cast(bf16x8, L);
}
// per-wave input-dtype flag: bf16 pairs always have low16 < 0x4000
__device__ __forceinline__ bool detect_bf16(const unsigned* x_raw, int lane) {
    unsigned v = x_raw[lane];
    return __ballot((v & 0xFFFFu) >= 0x4000u) == 0ull;
}

// ---------------- fused aux kernel ----------------
// blocks [0,2048)        : x transpose [B][L] -> xT [L][B] fp32 (vectorized)
// blocks [2048,2048+254) : fragment builder, ONE BLOCK PER SITE — stages the
//                          site's 8 KB core pair coalesced into padded LDS,
//                          computes the same pi-permuted hi/lo split dwords.
// block  2302            : small cores -> fp32, + WS_FLAG write
__global__ __launch_bounds__(256)
void aux_all(const void* __restrict__ x_in, const void* __restrict__ c0_in,
             const void* __restrict__ am_in, const void* __restrict__ cn_in,
             float* __restrict__ ws) {
    const int lane = threadIdx.x & 63;
    const bool bf = detect_bf16((const unsigned*)x_in, lane);
    const int b = blockIdx.x;

    if (b < 2048) {
        __shared__ float tile[64][65];          // tile[b_local][l_local], +1 pad
        const int bb = (b & 511) * 64;
        const int ll = (b >> 9) * 64;
        if (!bf) {
            const float4* x4 = (const float4*)x_in;   // row = 64 float4
            const int tr = threadIdx.x >> 4;    // 0..15
            const int q  = threadIdx.x & 15;    // 0..15
            #pragma unroll
            for (int u = 0; u < 4; ++u) {
                int row = tr + u * 16;
                float4 v = x4[(size_t)(bb + row) * (L_SITES / 4) + (ll / 4) + q];
                tile[row][q * 4 + 0] = v.x;
                tile[row][q * 4 + 1] = v.y;
                tile[row][q * 4 + 2] = v.z;
                tile[row][q * 4 + 3] = v.w;
            }
        } else {
            const uint4* x8 = (const uint4*)x_in;     // row = 32 uint4 (8 bf16 each)
            const int tr = threadIdx.x >> 3;    // 0..31
            const int q  = threadIdx.x & 7;     // 0..7
            #pragma unroll
            for (int u = 0; u < 2; ++u) {
                int row = tr + u * 32;
                uint4 v = x8[(size_t)(bb + row) * (L_SITES / 8) + (ll / 8) + q];
                const unsigned short* e = (const unsigned short*)&v;
                #pragma unroll
                for (int k = 0; k < 8; ++k) tile[row][q * 8 + k] = bf2f(e[k]);
            }
        }
        __syncthreads();
        {
            const int tr = threadIdx.x >> 4;    // 0..15
            const int q  = threadIdx.x & 15;    // 0..15
            float4* o4 = (float4*)(ws + WS_X);
            #pragma unroll
            for (int u = 0; u < 4; ++u) {
                int site = tr + u * 16;         // l_local
                float4 v;
                v.x = tile[q * 4 + 0][site];
                v.y = tile[q * 4 + 1][site];
                v.z = tile[q * 4 + 2][site];
                v.w = tile[q * 4 + 3][site];
                o4[((size_t)(ll + site) * B_TOTAL + bb) / 4 + q] = v;
            }
        }
    } else if (b < 2048 + N_MID) {
        const int t = b - 2048;
        __shared__ float amS[2][32][33];        // [f][a][m], +1 pad vs 4-way conflicts
        // coalesced stage: 2048 floats (site's [2][32][32] cores)
        if (!bf) {
            const float* src = (const float*)am_in + (size_t)t * 2048;
            for (int idx = threadIdx.x; idx < 2048; idx += 256) {
                amS[idx >> 10][(idx >> 5) & 31][idx & 31] = src[idx];
            }
        } else {
            const unsigned short* src = (const unsigned short*)am_in + (size_t)t * 2048;
            for (int idx = threadIdx.x; idx < 2048; idx += 256) {
                amS[idx >> 10][(idx >> 5) & 31][idx & 31] = bf2f(src[idx]);
            }
        }
        __syncthreads();
        #pragma unroll
        for (int u = 0; u < 2; ++u) {
            const int oi = threadIdx.x + 256 * u;   // 0..511
            const int q  = oi >> 6;                 // frag 0..7
            const int l  = oi & 63;                 // lane
            const int h  = q >> 2;
            const int kh = (q >> 1) & 1;
            const int p  = q & 1;
            const int m  = h * 16 + (l & 15);
            const int kb = (l >> 4) * 8;
            unsigned dw[4];
            #pragma unroll
            for (int d = 0; d < 4; ++d) {
                unsigned e01[2];
                #pragma unroll
                for (int s = 0; s < 2; ++s) {
                    int k = kb + 2 * d + s;         // k-slot 0..31
                    int a = pi_perm(k >> 3, k & 7); // PI-permuted contraction index
                    float v = amS[kh][a][m];
                    unsigned short hi = f2bf(v);
                    e01[s] = (p == 0) ? hi : f2bf(v - bf2f(hi));
                }
                dw[d] = e01[0] | (e01[1] << 16);
            }
            uint4 o; o.x = dw[0]; o.y = dw[1]; o.z = dw[2]; o.w = dw[3];
            ((uint4*)ws)[(size_t)(t * 8 + q) * 64 + l] = o;
        }
    } else {
        for (int i = threadIdx.x; i < 640; i += 256) {
            if (i < 64)
                ws[WS_C0 + i] = bf ? bf2f(((const unsigned short*)c0_in)[i])
                                   : ((const float*)c0_in)[i];
            ws[WS_CN + i] = bf ? bf2f(((const unsigned short*)cn_in)[i])
                               : ((const float*)cn_in)[i];
        }
        if (threadIdx.x == 0)
            *(unsigned*)(ws + WS_FLAG) = bf ? 1u : 0u;
    }
}

// ---------------- main chain kernel ----------------
// Round-4 structure (site steps, swapped-operand register chain, post-scale
// factorization) + sched_barrier(0) prefetch pinning (under test this round;
// r6's only failure was the HW-sincos accuracy, reverted here to __sincosf —
// bit-identical math to the passing r4/r5 kernels).
__global__ __launch_bounds__(256)
void mps_mfma(const float* __restrict__ ws, void* __restrict__ out) {
    const int lane = threadIdx.x & 63;
    const int w    = threadIdx.x >> 6;
    const int r    = lane & 15;
    const int quad = lane >> 4;
    const int b0   = (blockIdx.x * 4 + w) * 16;
    const float* __restrict__ xT = ws + WS_X;
    const uint4* __restrict__ BF = (const uint4*)ws;   // WS_FRAG = 0
    const int i = b0 + r;

    // ---- M0 in pi-layout: mm[j] = M0[b=r][a=pi(quad,j)] ----
    float mm[8];
    {
        float x0 = xT[i];
        float sn, cs; __sincosf(HALF_PI_F * x0, &sn, &cs);
        const float* c0 = ws + WS_C0;
        #pragma unroll
        for (int j = 0; j < 8; ++j) {
            int a = pi_perm(quad, j);
            mm[j] = cs * c0[a] + sn * c0[32 + a];
        }
    }

// one chain step: split M once -> 12 MFMA (4 indep 3-chains) -> post-scale
// combine with (CT,ST) -> optional norm.
// Qq roles: Q0=(h0,f0,hi) Q1=(h0,f0,lo) Q2=(h0,f1,hi) Q3=(h0,f1,lo)
//           Q4=(h1,f0,hi) Q5=(h1,f0,lo) Q6=(h1,f1,hi) Q7=(h1,f1,lo)
#define DO_STEP(CT, ST, Q0, Q1, Q2, Q3, Q4, Q5, Q6, Q7, DONORM)                    \
    {                                                                              \
        bf16x8 mh, ml;                                                             \
        split8(mm, mh, ml);                                                        \
        const f32x4 z = {0.f, 0.f, 0.f, 0.f};                                      \
        __builtin_amdgcn_s_setprio(1);                                             \
        f32x4 p00 = __builtin_amdgcn_mfma_f32_16x16x32_bf16(asbf(Q0), mh, z, 0, 0, 0);    \
        f32x4 p01 = __builtin_amdgcn_mfma_f32_16x16x32_bf16(asbf(Q2), mh, z, 0, 0, 0);    \
        f32x4 p10 = __builtin_amdgcn_mfma_f32_16x16x32_bf16(asbf(Q4), mh, z, 0, 0, 0);    \
        f32x4 p11 = __builtin_amdgcn_mfma_f32_16x16x32_bf16(asbf(Q6), mh, z, 0, 0, 0);    \
        p00 = __builtin_amdgcn_mfma_f32_16x16x32_bf16(asbf(Q1), mh, p00, 0, 0, 0); \
        p01 = __builtin_amdgcn_mfma_f32_16x16x32_bf16(asbf(Q3), mh, p01, 0, 0, 0); \
        p10 = __builtin_amdgcn_mfma_f32_16x16x32_bf16(asbf(Q5), mh, p10, 0, 0, 0); \
        p11 = __builtin_amdgcn_mfma_f32_16x16x32_bf16(asbf(Q7), mh, p11, 0, 0, 0); \
        p00 = __builtin_amdgcn_mfma_f32_16x16x32_bf16(asbf(Q0), ml, p00, 0, 0, 0); \
        p01 = __builtin_amdgcn_mfma_f32_16x16x32_bf16(asbf(Q2), ml, p01, 0, 0, 0); \
        p10 = __builtin_amdgcn_mfma_f32_16x16x32_bf16(asbf(Q4), ml, p10, 0, 0, 0); \
        p11 = __builtin_amdgcn_mfma_f32_16x16x32_bf16(asbf(Q6), ml, p11, 0, 0, 0); \
        __builtin_amdgcn_s_setprio(0);                                             \
        _Pragma("unroll")                                                          \
        for (int j = 0; j < 4; ++j) {                                              \
            mm[j]     = fmaf((ST), p01[j], (CT) * p00[j]);                         \
            mm[4 + j] = fmaf((ST), p11[j], (CT) * p10[j]);                         \
        }                                                                          \
        if (DONORM) {                                                              \
            float ss = 0.f;                                                        \
            _Pragma("unroll")                                                      \
            for (int j = 0; j < 8; ++j) ss = fmaf(mm[j], mm[j], ss);               \
            ss += __shfl_xor(ss, 16);                                              \
            ss += __shfl_xor(ss, 32);                                              \
            float kk = 1.0f / (sqrtf(ss) + EPS_NORM);                              \
            _Pragma("unroll")                                                      \
            for (int j = 0; j < 8; ++j) mm[j] *= kk;                               \
        }                                                                          \
    }

    // ---- pipeline prologue ----
    float ct0, st0;
    { float xc = xT[(size_t)B_TOTAL + i]; __sincosf(HALF_PI_F * xc, &st0, &ct0); }
    float x1 = xT[(size_t)2 * B_TOTAL + i];            // x of step 1

    const uint4* Ba = BF + lane;
    uint4 fa0 = Ba[0],   fa1 = Ba[64],  fa2 = Ba[128], fa3 = Ba[192];
    uint4 fa4 = Ba[256], fa5 = Ba[320], fa6 = Ba[384], fa7 = Ba[448];

    #pragma unroll 1
    for (int t = 0; t < N_MID; t += 2) {
        // ======== even step t: consumes (ct0,st0) + fa*; prefetch for t+1 ========
        const uint4* Bb = BF + (size_t)(t + 1) * 512 + lane;       // t+1 <= 253: valid
        uint4 fb0 = Bb[0],   fb1 = Bb[64],  fb2 = Bb[128], fb3 = Bb[192];
        uint4 fb4 = Bb[256], fb5 = Bb[320], fb6 = Bb[384], fb7 = Bb[448];
        float x2 = xT[(size_t)(t + 3) * B_TOTAL + i];              // x of step t+2 (t+3 <= 255)
        float ct1, st1; __sincosf(HALF_PI_F * x1, &st1, &ct1);     // factors for step t+1
        __builtin_amdgcn_sched_barrier(0);   // pin: loads for t+1 issue BEFORE step t

        DO_STEP(ct0, st0, fa0, fa1, fa2, fa3, fa4, fa5, fa6, fa7, false)

        // ======== odd step t+1: consumes (ct1,st1) + fb*; prefetch for t+2 ========
        const uint4* Bc = BF + (size_t)(t + 2) * 512 + lane;       // t=252 -> in-ws garbage, never consumed
        fa0 = Bc[0];   fa1 = Bc[64];  fa2 = Bc[128]; fa3 = Bc[192];
        fa4 = Bc[256]; fa5 = Bc[320]; fa6 = Bc[384]; fa7 = Bc[448];
        int xr = t + 4; if (xr > 255) xr = 255;                    // clamp (t=252 -> 256)
        x1 = xT[(size_t)xr * B_TOTAL + i];                         // x of step t+3
        __sincosf(HALF_PI_F * x2, &st0, &ct0);                     // factors for step t+2
        __builtin_amdgcn_sched_barrier(0);   // pin: loads for t+2 issue BEFORE step t+1

        DO_STEP(ct1, st1, fb0, fb1, fb2, fb3, fb4, fb5, fb6, fb7,
                (((t + 1) & 7) == 7) || (t + 1 == N_MID - 1))
    }
#undef DO_STEP

    // ---- readout: logits[r][c] = sum_a M[r][a]*(cN*KN0[a,c] + sN*KN1[a,c]) ----
    {
        float xN = xT[(size_t)(L_SITES - 1) * B_TOTAL + i];
        float sN, cN; __sincosf(HALF_PI_F * xN, &sN, &cN);
        const float* kn = ws + WS_CN;        // [f][a][10]
        float acc[10];
        #pragma unroll
        for (int c = 0; c < 10; ++c) acc[c] = 0.f;
        #pragma unroll
        for (int j = 0; j < 8; ++j) {
            int a = pi_perm(quad, j);
            float Ma = mm[j];
            #pragma unroll
            for (int c = 0; c < 10; ++c) {
                float fin = cN * kn[a * 10 + c] + sN * kn[320 + a * 10 + c];
                acc[c] = fmaf(Ma, fin, acc[c]);
            }
        }
        #pragma unroll
        for (int c = 0; c < 10; ++c) {
            acc[c] += __shfl_xor(acc[c], 16);
            acc[c] += __shfl_xor(acc[c], 32);
        }
        const unsigned bf = *(const unsigned*)(ws + WS_FLAG);
        if (quad == 0) {
            if (bf) {
                __hip_bfloat16* o = (__hip_bfloat16*)out;
                #pragma unroll
                for (int c = 0; c < 10; ++c)
                    o[(size_t)(b0 + r) * 10 + c] = __float2bfloat16(acc[c]);
            } else {
                float* o = (float*)out;
                #pragma unroll
                for (int c = 0; c < 10; ++c)
                    o[(size_t)(b0 + r) * 10 + c] = acc[c];
            }
        }
    }
}

// ---------------- launch ----------------
extern "C" void kernel_launch(void* const* d_in, const int* in_sizes, int n_in,
                              void* d_out, int out_size, void* d_ws, size_t ws_size,
                              hipStream_t stream) {
    float* ws = (float*)d_ws;
    aux_all<<<2048 + N_MID + 1, 256, 0, stream>>>(d_in[0], d_in[1], d_in[2], d_in[3], ws);
    // 512 blocks x 4 waves x 16 samples = 32768 samples; 2048 waves = 2 waves/SIMD
    mps_mfma<<<512, 256, 0, stream>>>(ws, d_out);
}